// Round 21
// baseline (288.208 us; speedup 1.0000x reference)
//
#include <hip/hip_runtime.h>

typedef unsigned short u16;
typedef _Float16 f16x8 __attribute__((ext_vector_type(8)));
typedef float f32x4 __attribute__((ext_vector_type(4)));

__device__ __forceinline__ u16 f2h(float f){
  _Float16 h = (_Float16)f; u16 u; __builtin_memcpy(&u, &h, 2); return u;
}
__device__ __forceinline__ float h2f(u16 u){
  _Float16 h; __builtin_memcpy(&h, &u, 2); return (float)h;
}
__device__ __forceinline__ unsigned pk2h(float a, float b){
  auto r = __builtin_amdgcn_cvt_pkrtz(a, b);
  unsigned u; __builtin_memcpy(&u, &r, 4); return u;
}
// raw v_rcp_f32 (1 VALU op); 1e-5 rel-err far below f16 output rounding.
__device__ __forceinline__ float sigm(float x){
  return __builtin_amdgcn_rcpf(1.0f + __expf(-x));
}
__device__ __forceinline__ f32x4 zero4(){ f32x4 z; z[0]=0.f; z[1]=0.f; z[2]=0.f; z[3]=0.f; return z; }

#define SWZ8(row,k) ((k) ^ (((row)&7)<<3))
// fragment index inside a 16-row x 32-k B/A tile set: frag=((n*4+kk)*4+hi)*16+col
#define FRAG(n,kk,hi,col) ((((n)*4+(kk))*4+(hi))*16+(col))

// ---------------- prep: weights straight to MFMA-fragment order ----------------
__global__ void k_prep(const float* __restrict__ p_in, const float* __restrict__ g_in,
                       const float* __restrict__ g_out, const float* __restrict__ p_out,
                       u16* __restrict__ W1F, u16* __restrict__ WgoF, u16* __restrict__ WpoF){
  int t = blockIdx.x*256 + threadIdx.x;
  if (t < 65536){
    int c = t >> 13, u = t & 8191, f = u >> 3, e = u & 7;
    int col = f & 15, hi = (f>>4)&3, kk = (f>>6)&3, n = f>>8;
    int d = c*32 + (n>>1)*16 + col, k = kk*32 + hi*8 + e;
    W1F[t] = f2h((n&1) ? g_in[d*128+k] : p_in[d*128+k]);
  } else if (t < 81920){
    int u = t - 65536, f = u>>3, e = u&7;
    int col = f&15, hi=(f>>4)&3, kk=(f>>6)&3, n=f>>8;
    WgoF[u] = f2h(g_out[(n*16+col)*128 + kk*32+hi*8+e]);
  } else if (t < 98304){
    int u = t - 81920, f = u>>3, e = u&7;
    int col=f&15, hi=(f>>4)&3, kk=(f>>6)&3, n=f>>8;
    WpoF[u] = f2h(p_out[(n*16+col)*128 + kk*32+hi*8+e]);
  }
}

// ---------------- S1: 64-row blocks -> 16.3KB LDS -> up to 8 blocks/CU ----------------
// R20: s1 occ 38% (33KB LDS caps 4 blocks). Halved tile doubles resident waves;
// per-wave state halves (af[4], acc[4]) so no register trap.
__global__ __launch_bounds__(256,2) void k_s1(
    const float* __restrict__ x, const float* __restrict__ mask,
    const float* __restrict__ nw, const float* __restrict__ nb,
    const u16* __restrict__ W1F,
    u16* __restrict__ a_t, u16* __restrict__ b_t, u16* __restrict__ x16f)
{
  __shared__ u16 xh_s[64*128];    // 16KB: x_in f16; first 8KB reused as dbuf staging
  __shared__ float mask_s[64];

  const int tid = threadIdx.x, lane = tid & 63, w = tid >> 6;
  const int col = lane & 15, hi = lane >> 4;
  const int b = blockIdx.x;
  const int r0 = b * 64;

  if (tid < 64) mask_s[tid] = mask[r0 + tid];

  // LayerNorm — 4 rows/wave-iter (16 lanes/row, 8 f32/lane, coalesced); 4 iters
  {
    const int g = lane >> 4, cl = lane & 15;
    float4 nwa = *(const float4*)(nw + cl*8);
    float4 nwb = *(const float4*)(nw + cl*8 + 4);
    float4 nba = *(const float4*)(nb + cl*8);
    float4 nbb = *(const float4*)(nb + cl*8 + 4);
    #pragma unroll
    for (int it = 0; it < 4; ++it){
      int row = w*16 + it*4 + g;
      const float* xr = x + (size_t)(r0+row)*128 + cl*8;
      float4 xa = *(const float4*)xr;
      float4 xb = *(const float4*)(xr + 4);
      float s = ((xa.x+xa.y)+(xa.z+xa.w)) + ((xb.x+xb.y)+(xb.z+xb.w));
      float q = xa.x*xa.x; q = fmaf(xa.y,xa.y,q); q = fmaf(xa.z,xa.z,q); q = fmaf(xa.w,xa.w,q);
      q = fmaf(xb.x,xb.x,q); q = fmaf(xb.y,xb.y,q); q = fmaf(xb.z,xb.z,q); q = fmaf(xb.w,xb.w,q);
      #pragma unroll
      for (int off = 1; off < 16; off <<= 1){ s += __shfl_xor(s, off); q += __shfl_xor(q, off); }
      float mu = s * 0.0078125f;
      float rs = rsqrtf(fmaxf(q*0.0078125f - mu*mu, 0.f) + 1e-5f);
      uint4 pv;
      pv.x = pk2h((xa.x-mu)*rs*nwa.x+nba.x, (xa.y-mu)*rs*nwa.y+nba.y);
      pv.y = pk2h((xa.z-mu)*rs*nwa.z+nba.z, (xa.w-mu)*rs*nwa.w+nba.w);
      pv.z = pk2h((xb.x-mu)*rs*nwb.x+nbb.x, (xb.y-mu)*rs*nwb.y+nbb.y);
      pv.w = pk2h((xb.z-mu)*rs*nwb.z+nbb.z, (xb.w-mu)*rs*nwb.w+nbb.w);
      *(uint4*)(&xh_s[row*128 + SWZ8(row, cl*8)]) = pv;
    }
  }
  // wave-private band: no barrier needed before own-fragment reads

  // A-fragments register-cached once (16 rows/wave -> af[4])
  f16x8 af[4];
  #pragma unroll
  for (int kk = 0; kk < 4; ++kk){
    int row = w*16 + col;
    af[kk] = *(const f16x8*)(&xh_s[row*128 + SWZ8(row, kk*32 + hi*8)]);
  }
  float mk[4];
  #pragma unroll
  for (int j = 0; j < 4; ++j) mk[j] = mask_s[w*16 + hi*4 + j];

  // x_in -> x16f in fragment order: superblock b>>1, band n = (b&1)*4 + w
  {
    u16* dst = x16f + (size_t)(b >> 1)*16384;
    #pragma unroll
    for (int kk = 0; kk < 4; ++kk)
      *(f16x8*)(dst + (size_t)FRAG((b&1)*4 + w, kk, hi, col)*8) = af[kk];
  }
  __syncthreads();   // all waves' af cached -> xh_s reusable as staging

  for (int c = 0; c < 8; ++c){
    f32x4 acc[4];
    #pragma unroll
    for (int n = 0; n < 4; ++n) acc[n] = zero4();

    #pragma unroll
    for (int kk = 0; kk < 4; ++kk){
      f16x8 bf[4];
      #pragma unroll
      for (int n = 0; n < 4; ++n)
        bf[n] = *(const f16x8*)(W1F + c*8192 + (size_t)FRAG(n,kk,hi,col)*8);
      #pragma unroll
      for (int n = 0; n < 4; ++n)
        acc[n] = __builtin_amdgcn_mfma_f32_16x16x32_f16(af[kk], bf[n], acc[n], 0, 0, 0);
    }

    // h = p * sigmoid(g) * mask; staging swizzled by 8-row granule
    u16* hbuf = xh_s + (c & 1)*2048;
    #pragma unroll
    for (int t2 = 0; t2 < 2; ++t2){
      f32x4 pv = acc[2*t2], gv = acc[2*t2+1];
      int dl = t2*16 + col;
      int rb = w*16 + hi*4;
      int ad = dl*64 + (rb ^ ((dl & 7) << 3));
      float h0 = pv[0]*sigm(gv[0])*mk[0];
      float h1 = pv[1]*sigm(gv[1])*mk[1];
      float h2 = pv[2]*sigm(gv[2])*mk[2];
      float h3 = pv[3]*sigm(gv[3])*mk[3];
      uint2 uv; uv.x = pk2h(h0, h1); uv.y = pk2h(h2, h3);
      *(uint2*)(&hbuf[ad]) = uv;
    }
    __syncthreads();            // hbuf(c) visible; prior reads of this buf done 1 barrier ago
    {
      int dl = tid >> 3, seg = (tid & 7)*8;
      int dg = c*32 + dl;
      u16* dst = (dg < 128 ? a_t + (size_t)dg*262144 : b_t + (size_t)(dg-128)*262144) + r0;
      int rr = seg ^ ((dl & 7) << 3);
      uint4 v0 = *(const uint4*)(&hbuf[dl*64 + rr]);
      *(uint4*)(dst + seg) = v0;
    }
  }
}

// ---------------- S2: 128 batched NT-GEMMs, dbuf pipeline ----------------
__global__ __launch_bounds__(256,4) void k_s2(
    const u16* __restrict__ a_t, const u16* __restrict__ b_t, u16* __restrict__ t_dm)
{
  __shared__ u16 AB_s[2][2][4096];

  const int tid = threadIdx.x, lane = tid & 63, w = tid >> 6;
  const int col = lane & 15, hi = lane >> 4;

  int bid = blockIdx.x + (blockIdx.y << 4);
  int sw = (bid & 7)*256 + (bid >> 3);
  const int d = sw >> 4;
  const int tile = sw & 15;
  const int ti = (tile >> 2) * 128, tj = (tile & 3) * 128;
  const u16* Ab = a_t + (size_t)d * 262144;
  const u16* Bb = b_t + (size_t)d * 262144;
  const int wr = (w >> 1) * 64, wc = (w & 1) * 64;

  f32x4 acc[4][4];
  #pragma unroll
  for (int m=0;m<4;m++){
    #pragma unroll
    for (int n=0;n<4;n++) acc[m][n] = zero4();
  }

  const int srow = lane >> 2;
  const int scol = (lane & 3) * 8;

  auto STAGE = [&](int buf, int k0){
    #pragma unroll
    for (int j = 0; j < 2; ++j){
      int chunk = w*2 + j;
      int row = chunk*16 + srow;
      int e = scol ^ ((((row >> 1) & 3)) << 3);
      const unsigned int* gpA = (const unsigned int*)(Ab + (size_t)(ti + row)*512 + k0 + e);
      unsigned int* lpA = (unsigned int*)(&AB_s[buf][0][chunk*512]);
      __builtin_amdgcn_global_load_lds((const __attribute__((address_space(1))) unsigned int*)gpA,
                                       (__attribute__((address_space(3))) unsigned int*)lpA, 16, 0, 0);
      const unsigned int* gpB = (const unsigned int*)(Bb + (size_t)(tj + row)*512 + k0 + e);
      unsigned int* lpB = (unsigned int*)(&AB_s[buf][1][chunk*512]);
      __builtin_amdgcn_global_load_lds((const __attribute__((address_space(1))) unsigned int*)gpB,
                                       (__attribute__((address_space(3))) unsigned int*)lpB, 16, 0, 0);
    }
  };

  STAGE(0, 0);
  int cur = 0;
  for (int k0 = 0; k0 < 512; k0 += 32){
    __syncthreads();
    if (k0 + 32 < 512) STAGE(cur ^ 1, k0 + 32);
    f16x8 af[4], bfv[4];
    #pragma unroll
    for (int m=0;m<4;m++){
      int row = wr + m*16 + col;
      af[m] = *(const f16x8*)(&AB_s[cur][0][row*32 + (hi*8 ^ ((((row>>1)&3))<<3))]);
    }
    #pragma unroll
    for (int n=0;n<4;n++){
      int row = wc + n*16 + col;
      bfv[n] = *(const f16x8*)(&AB_s[cur][1][row*32 + (hi*8 ^ ((((row>>1)&3))<<3))]);
    }
    #pragma unroll
    for (int m=0;m<4;m++){
      #pragma unroll
      for (int n=0;n<4;n++)
        acc[m][n] = __builtin_amdgcn_mfma_f32_16x16x32_f16(af[m], bfv[n], acc[m][n], 0, 0, 0);
    }
    cur ^= 1;
  }

  u16* C_s = &AB_s[0][0][0];
  __syncthreads();
  u16* dst0 = t_dm + (size_t)d*262144 + (size_t)ti*512 + tj;
  #pragma unroll
  for (int h = 0; h < 2; ++h){
    if ((w >> 1) == h){
      #pragma unroll
      for (int m=0;m<4;m++){
        #pragma unroll
        for (int n=0;n<4;n++){
          #pragma unroll
          for (int j=0;j<4;j++){
            int row = m*16 + hi*4 + j, cl = wc + n*16 + col;
            C_s[row*136 + cl] = f2h(acc[m][n][j]);
          }
        }
      }
    }
    __syncthreads();
    #pragma unroll
    for (int s=0;s<4;s++){
      int gi = s*256 + tid;
      int row = gi >> 4, seg = (gi & 15) * 8;
      *(uint4*)(dst0 + (size_t)(h*64 + row)*512 + seg) = *(const uint4*)(&C_s[row*136 + seg]);
    }
    if (h == 0) __syncthreads();
  }
}

// ---------------- S3: two n-half passes (R20-measured best) ----------------
#define PST 68
__global__ __launch_bounds__(256,2) void k_s3(
    const u16* __restrict__ t_dm, const u16* __restrict__ x16f,
    const u16* __restrict__ WgoF, const u16* __restrict__ WpoF,
    const float* __restrict__ nw, const float* __restrict__ nb,
    float* __restrict__ out)
{
  __shared__ u16 t_s[128*128];      // 32KB LN'd t tile (SWZ8)
  __shared__ u16 prod[2][128*PST];  // 2 x 17KB gated product halves

  const int tid = threadIdx.x, lane = tid & 63, w = tid >> 6;
  const int col = lane & 15, hi = lane >> 4;
  const size_t rbase = (size_t)blockIdx.x * 128;

  const int dblk = tid >> 4, jblk = tid & 15;
  const u16* tsrc = t_dm + (size_t)(dblk*8)*262144 + rbase + jblk*8;
  uint4 rv[8];
  #pragma unroll
  for (int r=0;r<8;r++) rv[r] = *(const uint4*)(tsrc + (size_t)r*262144);

  f16x8 af[2][4];
  {
    const u16* base = x16f + (size_t)blockIdx.x*16384;
    #pragma unroll
    for (int m=0;m<2;m++)
      #pragma unroll
      for (int kk=0;kk<4;kk++)
        af[m][kk] = *(const f16x8*)(base + (size_t)FRAG(w*2+m, kk, hi, col)*8);
  }

  {
    const unsigned* pr = (const unsigned*)rv;
    #pragma unroll
    for (int jj=0;jj<8;jj++){
      int j = (jj + jblk) & 7;
      unsigned sel = (j&1) ? 0x07060302u : 0x05040100u;
      int dw = j >> 1;
      uint4 ov;
      ov.x = __builtin_amdgcn_perm(pr[4+dw],  pr[0+dw],  sel);
      ov.y = __builtin_amdgcn_perm(pr[12+dw], pr[8+dw],  sel);
      ov.z = __builtin_amdgcn_perm(pr[20+dw], pr[16+dw], sel);
      ov.w = __builtin_amdgcn_perm(pr[28+dw], pr[24+dw], sel);
      int row = jblk*8 + j;
      *(uint4*)(&t_s[row*128 + SWZ8(row, dblk*8)]) = ov;
    }
  }
  __syncthreads();

  {
    int j = tid >> 1, dh = (tid & 1) * 64;
    float s = 0.f, q = 0.f;
    #pragma unroll
    for (int sc=0;sc<8;sc++){
      uint4 v = *(const uint4*)(&t_s[j*128 + SWZ8(j, dh + sc*8)]);
      const u16* ev = (const u16*)&v;
      #pragma unroll
      for (int u=0;u<8;u++){ float f = h2f(ev[u]); s += f; q = fmaf(f,f,q); }
    }
    s += __shfl_xor(s, 1); q += __shfl_xor(q, 1);
    float mu = s * 0.0078125f;
    float rs = rsqrtf(fmaxf(q*0.0078125f - mu*mu, 0.f) + 1e-5f);
    #pragma unroll
    for (int sc=0;sc<8;sc++){
      int db = dh + sc*8;
      u16* p = &t_s[j*128 + SWZ8(j, db)];
      uint4 v = *(uint4*)p;
      u16* ev = (u16*)&v;
      float4 w0 = *(const float4*)(nw + db);
      float4 w1 = *(const float4*)(nw + db + 4);
      float4 b0 = *(const float4*)(nb + db);
      float4 b1 = *(const float4*)(nb + db + 4);
      float wv[8] = {w0.x,w0.y,w0.z,w0.w,w1.x,w1.y,w1.z,w1.w};
      float bv[8] = {b0.x,b0.y,b0.z,b0.w,b1.x,b1.y,b1.z,b1.w};
      #pragma unroll
      for (int u=0;u<8;u++){
        float f = (h2f(ev[u]) - mu)*rs*wv[u] + bv[u];
        ev[u] = f2h(f);
      }
      *(uint4*)p = v;
    }
  }
  __syncthreads();

  #pragma unroll
  for (int ph = 0; ph < 2; ++ph){
    unsigned gt[2][4][2];
    {
      f32x4 gacc[2][4];
      #pragma unroll
      for (int m=0;m<2;m++)
        #pragma unroll
        for (int n=0;n<4;n++) gacc[m][n] = zero4();
      #pragma unroll
      for (int kk=0;kk<4;kk++){
        #pragma unroll
        for (int n=0;n<4;n++){
          f16x8 bv = *(const f16x8*)(WgoF + (size_t)FRAG(ph*4+n,kk,hi,col)*8);
          #pragma unroll
          for (int m=0;m<2;m++)
            gacc[m][n] = __builtin_amdgcn_mfma_f32_16x16x32_f16(af[m][kk], bv, gacc[m][n], 0, 0, 0);
        }
      }
      #pragma unroll
      for (int m=0;m<2;m++)
        #pragma unroll
        for (int n=0;n<4;n++){
          gt[m][n][0] = pk2h(sigm(gacc[m][n][0]), sigm(gacc[m][n][1]));
          gt[m][n][1] = pk2h(sigm(gacc[m][n][2]), sigm(gacc[m][n][3]));
        }
    }
    {
      f32x4 acc[2][4];
      #pragma unroll
      for (int m=0;m<2;m++)
        #pragma unroll
        for (int n=0;n<4;n++) acc[m][n] = zero4();
      #pragma unroll
      for (int kk=0;kk<4;kk++){
        f16x8 a2[2];
        #pragma unroll
        for (int m=0;m<2;m++){
          int row = w*32 + m*16 + col;
          a2[m] = *(const f16x8*)(&t_s[row*128 + SWZ8(row, kk*32 + hi*8)]);
        }
        #pragma unroll
        for (int n=0;n<4;n++){
          f16x8 bv = *(const f16x8*)(WpoF + (size_t)FRAG(ph*4+n,kk,hi,col)*8);
          #pragma unroll
          for (int m=0;m<2;m++)
            acc[m][n] = __builtin_amdgcn_mfma_f32_16x16x32_f16(a2[m], bv, acc[m][n], 0, 0, 0);
        }
      }
      #pragma unroll
      for (int m=0;m<2;m++)
        #pragma unroll
        for (int n=0;n<4;n++)
          #pragma unroll
          for (int j=0;j<4;j++){
            int row = w*32 + m*16 + hi*4 + j, cl = n*16 + col;
            float g = h2f((u16)(gt[m][n][j>>1] >> ((j&1)*16)));
            prod[ph][row*PST + cl] = f2h(acc[m][n][j] * g);
          }
    }
  }
  __syncthreads();

  {
    #pragma unroll
    for (int s=0;s<16;s++){
      int idx = s*256 + tid;
      int row = idx >> 5, c4 = (idx & 31) << 2;
      int ph = c4 >> 6, cc = c4 & 63;
      const u16* p = &prod[ph][row*PST + cc];
      uint2 cv = *(const uint2*)p;
      const u16* ce = (const u16*)&cv;
      float4 o;
      o.x = h2f(ce[0]); o.y = h2f(ce[1]); o.z = h2f(ce[2]); o.w = h2f(ce[3]);
      *(float4*)(out + (rbase + row)*128 + c4) = o;
    }
  }
}

extern "C" void kernel_launch(void* const* d_in, const int* in_sizes, int n_in,
                              void* d_out, int out_size, void* d_ws, size_t ws_size,
                              hipStream_t stream){
  const float* x    = (const float*)d_in[0];
  const float* mask = (const float*)d_in[1];
  const float* niw  = (const float*)d_in[2];
  const float* nib  = (const float*)d_in[3];
  const float* piw  = (const float*)d_in[4];
  const float* giw  = (const float*)d_in[5];
  const float* now  = (const float*)d_in[6];
  const float* nob  = (const float*)d_in[7];
  const float* pow_ = (const float*)d_in[8];
  const float* gow  = (const float*)d_in[9];
  float* out = (float*)d_out;

  char* ws = (char*)d_ws;
  u16* a_t  = (u16*)(ws);                          // 64 MB  [128][262144]
  u16* b_t  = (u16*)(ws + (size_t)67108864);       // 64 MB
  u16* t_dm = (u16*)(ws + (size_t)134217728);      // 64 MB  [128][512][512]
  u16* x16f = (u16*)(ws + (size_t)201326592);      // 64 MB  frag-order x_in
  u16* W1F  = (u16*)(ws + (size_t)268435456);      // 128 KB frag-order
  u16* WgoF = W1F + 65536;                         // 32 KB
  u16* WpoF = WgoF + 16384;                        // 32 KB

  k_prep<<<384, 256, 0, stream>>>(piw, giw, gow, pow_, W1F, WgoF, WpoF);
  k_s1<<<4096, 256, 0, stream>>>(x, mask, niw, nib, W1F, a_t, b_t, x16f);
  k_s2<<<dim3(16,128), 256, 0, stream>>>(a_t, b_t, t_dm);
  k_s3<<<2048, 256, 0, stream>>>(t_dm, x16f, WgoF, WpoF, now, nob, out);
}

// Round 23
// 268.029 us; speedup vs baseline: 1.0753x; 1.0753x over previous
//
#include <hip/hip_runtime.h>

typedef unsigned short u16;
typedef _Float16 f16x8 __attribute__((ext_vector_type(8)));
typedef float f32x4 __attribute__((ext_vector_type(4)));
typedef unsigned u32x4 __attribute__((ext_vector_type(4)));
typedef unsigned u32x2 __attribute__((ext_vector_type(2)));

__device__ __forceinline__ u16 f2h(float f){
  _Float16 h = (_Float16)f; u16 u; __builtin_memcpy(&u, &h, 2); return u;
}
__device__ __forceinline__ float h2f(u16 u){
  _Float16 h; __builtin_memcpy(&h, &u, 2); return (float)h;
}
__device__ __forceinline__ unsigned pk2h(float a, float b){
  auto r = __builtin_amdgcn_cvt_pkrtz(a, b);
  unsigned u; __builtin_memcpy(&u, &r, 4); return u;
}
// raw v_rcp_f32 (1 VALU op); 1e-5 rel-err far below f16 output rounding.
__device__ __forceinline__ float sigm(float x){
  return __builtin_amdgcn_rcpf(1.0f + __expf(-x));
}
__device__ __forceinline__ f32x4 zero4(){ f32x4 z; z[0]=0.f; z[1]=0.f; z[2]=0.f; z[3]=0.f; return z; }
// streaming (nontemporal) stores via clang ext_vector types (HIP uint4 is a
// struct and is rejected by the builtin).
__device__ __forceinline__ void st_nt4(u16* p, uint4 v){
  u32x4 t; __builtin_memcpy(&t, &v, 16);
  __builtin_nontemporal_store(t, (u32x4*)p);
}
__device__ __forceinline__ void st_ntf4(float* p, float4 v){
  f32x4 t; __builtin_memcpy(&t, &v, 16);
  __builtin_nontemporal_store(t, (f32x4*)p);
}

#define SWZ8(row,k) ((k) ^ (((row)&7)<<3))
// fragment index inside a 16-row x 32-k B/A tile set: frag=((n*4+kk)*4+hi)*16+col
#define FRAG(n,kk,hi,col) ((((n)*4+(kk))*4+(hi))*16+(col))

// ---------------- prep: weights straight to MFMA-fragment order ----------------
__global__ void k_prep(const float* __restrict__ p_in, const float* __restrict__ g_in,
                       const float* __restrict__ g_out, const float* __restrict__ p_out,
                       u16* __restrict__ W1F, u16* __restrict__ WgoF, u16* __restrict__ WpoF){
  int t = blockIdx.x*256 + threadIdx.x;
  if (t < 65536){
    int c = t >> 13, u = t & 8191, f = u >> 3, e = u & 7;
    int col = f & 15, hi = (f>>4)&3, kk = (f>>6)&3, n = f>>8;
    int d = c*32 + (n>>1)*16 + col, k = kk*32 + hi*8 + e;
    W1F[t] = f2h((n&1) ? g_in[d*128+k] : p_in[d*128+k]);
  } else if (t < 81920){
    int u = t - 65536, f = u>>3, e = u&7;
    int col = f&15, hi=(f>>4)&3, kk=(f>>6)&3, n=f>>8;
    WgoF[u] = f2h(g_out[(n*16+col)*128 + kk*32+hi*8+e]);
  } else if (t < 98304){
    int u = t - 81920, f = u>>3, e = u&7;
    int col=f&15, hi=(f>>4)&3, kk=(f>>6)&3, n=f>>8;
    WpoF[u] = f2h(p_out[(n*16+col)*128 + kk*32+hi*8+e]);
  }
}

// ---------------- S1: LN + paired in-projection (R20-best + NT stores) ----------------
__global__ __launch_bounds__(256,2) void k_s1(
    const float* __restrict__ x, const float* __restrict__ mask,
    const float* __restrict__ nw, const float* __restrict__ nb,
    const u16* __restrict__ W1F,
    u16* __restrict__ a_t, u16* __restrict__ b_t, u16* __restrict__ x16f)
{
  __shared__ u16 xh_s[128*128];   // 32KB: x_in f16; first 8KB reused as dbuf staging
  __shared__ float mask_s[128];

  const int tid = threadIdx.x, lane = tid & 63, w = tid >> 6;
  const int col = lane & 15, hi = lane >> 4;
  const int r0 = blockIdx.x * 128;

  if (tid < 128) mask_s[tid] = mask[r0 + tid];

  // LayerNorm — 4 rows/wave in parallel (16 lanes/row, 8 f32/lane, coalesced)
  {
    const int g = lane >> 4, cl = lane & 15;
    float4 nwa = *(const float4*)(nw + cl*8);
    float4 nwb = *(const float4*)(nw + cl*8 + 4);
    float4 nba = *(const float4*)(nb + cl*8);
    float4 nbb = *(const float4*)(nb + cl*8 + 4);
    #pragma unroll
    for (int it = 0; it < 8; ++it){
      int row = w*32 + it*4 + g;
      const float* xr = x + (size_t)(r0+row)*128 + cl*8;
      float4 xa = *(const float4*)xr;
      float4 xb = *(const float4*)(xr + 4);
      float s = ((xa.x+xa.y)+(xa.z+xa.w)) + ((xb.x+xb.y)+(xb.z+xb.w));
      float q = xa.x*xa.x; q = fmaf(xa.y,xa.y,q); q = fmaf(xa.z,xa.z,q); q = fmaf(xa.w,xa.w,q);
      q = fmaf(xb.x,xb.x,q); q = fmaf(xb.y,xb.y,q); q = fmaf(xb.z,xb.z,q); q = fmaf(xb.w,xb.w,q);
      #pragma unroll
      for (int off = 1; off < 16; off <<= 1){ s += __shfl_xor(s, off); q += __shfl_xor(q, off); }
      float mu = s * 0.0078125f;
      float rs = rsqrtf(fmaxf(q*0.0078125f - mu*mu, 0.f) + 1e-5f);
      uint4 pv;
      pv.x = pk2h((xa.x-mu)*rs*nwa.x+nba.x, (xa.y-mu)*rs*nwa.y+nba.y);
      pv.y = pk2h((xa.z-mu)*rs*nwa.z+nba.z, (xa.w-mu)*rs*nwa.w+nba.w);
      pv.z = pk2h((xb.x-mu)*rs*nwb.x+nbb.x, (xb.y-mu)*rs*nwb.y+nbb.y);
      pv.w = pk2h((xb.z-mu)*rs*nwb.z+nbb.z, (xb.w-mu)*rs*nwb.w+nbb.w);
      *(uint4*)(&xh_s[row*128 + SWZ8(row, cl*8)]) = pv;
    }
  }
  __syncthreads();

  // A-fragments register-cached once
  f16x8 af[2][4];
  #pragma unroll
  for (int m = 0; m < 2; ++m){
    #pragma unroll
    for (int kk = 0; kk < 4; ++kk){
      int row = w*32 + m*16 + col;
      af[m][kk] = *(const f16x8*)(&xh_s[row*128 + SWZ8(row, kk*32 + hi*8)]);
    }
  }
  float mk[2][4];
  #pragma unroll
  for (int m = 0; m < 2; ++m)
    #pragma unroll
    for (int j = 0; j < 4; ++j) mk[m][j] = mask_s[w*32 + m*16 + hi*4 + j];

  // x_in -> x16f in fragment order (1KB/wave-instr coalesced, NT)
  {
    u16* dst = x16f + (size_t)blockIdx.x*16384;
    #pragma unroll
    for (int m = 0; m < 2; ++m)
      #pragma unroll
      for (int kk = 0; kk < 4; ++kk){
        uint4 v; __builtin_memcpy(&v, &af[m][kk], 16);
        st_nt4(dst + (size_t)FRAG(w*2+m, kk, hi, col)*8, v);
      }
  }
  __syncthreads();   // af cached -> xh_s reusable as staging

  for (int c = 0; c < 8; ++c){
    f32x4 acc[2][4];
    #pragma unroll
    for (int m = 0; m < 2; ++m)
      #pragma unroll
      for (int n = 0; n < 4; ++n) acc[m][n] = zero4();

    #pragma unroll
    for (int kk = 0; kk < 4; ++kk){
      f16x8 bf[4];
      #pragma unroll
      for (int n = 0; n < 4; ++n)
        bf[n] = *(const f16x8*)(W1F + c*8192 + (size_t)FRAG(n,kk,hi,col)*8);
      #pragma unroll
      for (int m = 0; m < 2; ++m)
        #pragma unroll
        for (int n = 0; n < 4; ++n)
          acc[m][n] = __builtin_amdgcn_mfma_f32_16x16x32_f16(af[m][kk], bf[n], acc[m][n], 0, 0, 0);
    }

    u16* hbuf = xh_s + (c & 1)*4096;
    #pragma unroll
    for (int m = 0; m < 2; ++m){
      #pragma unroll
      for (int t2 = 0; t2 < 2; ++t2){
        f32x4 pv = acc[m][2*t2], gv = acc[m][2*t2+1];
        int dl = t2*16 + col;
        int rb = w*32 + m*16 + hi*4;
        int ad = dl*128 + (rb ^ ((dl & 15) << 3));
        float h0 = pv[0]*sigm(gv[0])*mk[m][0];
        float h1 = pv[1]*sigm(gv[1])*mk[m][1];
        float h2 = pv[2]*sigm(gv[2])*mk[m][2];
        float h3 = pv[3]*sigm(gv[3])*mk[m][3];
        uint2 uv; uv.x = pk2h(h0, h1); uv.y = pk2h(h2, h3);
        *(uint2*)(&hbuf[ad]) = uv;
      }
    }
    __syncthreads();
    {
      int dl = tid >> 3, seg = (tid & 7)*16;
      int dg = c*32 + dl;
      u16* dst = (dg < 128 ? a_t + (size_t)dg*262144 : b_t + (size_t)(dg-128)*262144) + r0;
      int sw = (dl & 15) << 3;
      uint4 v0 = *(const uint4*)(&hbuf[dl*128 + (seg ^ sw)]);
      uint4 v1 = *(const uint4*)(&hbuf[dl*128 + ((seg + 8) ^ sw)]);
      st_nt4(dst + seg,     v0);
      st_nt4(dst + seg + 8, v1);
    }
  }
}

// ---------------- S2: 128 batched NT-GEMMs, dbuf pipeline (NT t_dm store) ----------------
__global__ __launch_bounds__(256,4) void k_s2(
    const u16* __restrict__ a_t, const u16* __restrict__ b_t, u16* __restrict__ t_dm)
{
  __shared__ u16 AB_s[2][2][4096];

  const int tid = threadIdx.x, lane = tid & 63, w = tid >> 6;
  const int col = lane & 15, hi = lane >> 4;

  int bid = blockIdx.x + (blockIdx.y << 4);
  int sw = (bid & 7)*256 + (bid >> 3);
  const int d = sw >> 4;
  const int tile = sw & 15;
  const int ti = (tile >> 2) * 128, tj = (tile & 3) * 128;
  const u16* Ab = a_t + (size_t)d * 262144;
  const u16* Bb = b_t + (size_t)d * 262144;
  const int wr = (w >> 1) * 64, wc = (w & 1) * 64;

  f32x4 acc[4][4];
  #pragma unroll
  for (int m=0;m<4;m++){
    #pragma unroll
    for (int n=0;n<4;n++) acc[m][n] = zero4();
  }

  const int srow = lane >> 2;
  const int scol = (lane & 3) * 8;

  auto STAGE = [&](int buf, int k0){
    #pragma unroll
    for (int j = 0; j < 2; ++j){
      int chunk = w*2 + j;
      int row = chunk*16 + srow;
      int e = scol ^ ((((row >> 1) & 3)) << 3);
      const unsigned int* gpA = (const unsigned int*)(Ab + (size_t)(ti + row)*512 + k0 + e);
      unsigned int* lpA = (unsigned int*)(&AB_s[buf][0][chunk*512]);
      __builtin_amdgcn_global_load_lds((const __attribute__((address_space(1))) unsigned int*)gpA,
                                       (__attribute__((address_space(3))) unsigned int*)lpA, 16, 0, 0);
      const unsigned int* gpB = (const unsigned int*)(Bb + (size_t)(tj + row)*512 + k0 + e);
      unsigned int* lpB = (unsigned int*)(&AB_s[buf][1][chunk*512]);
      __builtin_amdgcn_global_load_lds((const __attribute__((address_space(1))) unsigned int*)gpB,
                                       (__attribute__((address_space(3))) unsigned int*)lpB, 16, 0, 0);
    }
  };

  STAGE(0, 0);
  int cur = 0;
  for (int k0 = 0; k0 < 512; k0 += 32){
    __syncthreads();
    if (k0 + 32 < 512) STAGE(cur ^ 1, k0 + 32);
    f16x8 af[4], bfv[4];
    #pragma unroll
    for (int m=0;m<4;m++){
      int row = wr + m*16 + col;
      af[m] = *(const f16x8*)(&AB_s[cur][0][row*32 + (hi*8 ^ ((((row>>1)&3))<<3))]);
    }
    #pragma unroll
    for (int n=0;n<4;n++){
      int row = wc + n*16 + col;
      bfv[n] = *(const f16x8*)(&AB_s[cur][1][row*32 + (hi*8 ^ ((((row>>1)&3))<<3))]);
    }
    #pragma unroll
    for (int m=0;m<4;m++){
      #pragma unroll
      for (int n=0;n<4;n++)
        acc[m][n] = __builtin_amdgcn_mfma_f32_16x16x32_f16(af[m], bfv[n], acc[m][n], 0, 0, 0);
    }
    cur ^= 1;
  }

  u16* C_s = &AB_s[0][0][0];
  __syncthreads();
  u16* dst0 = t_dm + (size_t)d*262144 + (size_t)ti*512 + tj;
  #pragma unroll
  for (int h = 0; h < 2; ++h){
    if ((w >> 1) == h){
      #pragma unroll
      for (int m=0;m<4;m++){
        #pragma unroll
        for (int n=0;n<4;n++){
          #pragma unroll
          for (int j=0;j<4;j++){
            int row = m*16 + hi*4 + j, cl = wc + n*16 + col;
            C_s[row*136 + cl] = f2h(acc[m][n][j]);
          }
        }
      }
    }
    __syncthreads();
    #pragma unroll
    for (int s=0;s<4;s++){
      int gi = s*256 + tid;
      int row = gi >> 4, seg = (gi & 15) * 8;
      st_nt4(dst0 + (size_t)(h*64 + row)*512 + seg, *(const uint4*)(&C_s[row*136 + seg]));
    }
    if (h == 0) __syncthreads();
  }
}

// ---------------- S3: two n-half passes (R20-best + NT out store) ----------------
#define PST 68
__global__ __launch_bounds__(256,2) void k_s3(
    const u16* __restrict__ t_dm, const u16* __restrict__ x16f,
    const u16* __restrict__ WgoF, const u16* __restrict__ WpoF,
    const float* __restrict__ nw, const float* __restrict__ nb,
    float* __restrict__ out)
{
  __shared__ u16 t_s[128*128];      // 32KB LN'd t tile (SWZ8)
  __shared__ u16 prod[2][128*PST];  // 2 x 17KB gated product halves

  const int tid = threadIdx.x, lane = tid & 63, w = tid >> 6;
  const int col = lane & 15, hi = lane >> 4;
  const size_t rbase = (size_t)blockIdx.x * 128;

  const int dblk = tid >> 4, jblk = tid & 15;
  const u16* tsrc = t_dm + (size_t)(dblk*8)*262144 + rbase + jblk*8;
  uint4 rv[8];
  #pragma unroll
  for (int r=0;r<8;r++) rv[r] = *(const uint4*)(tsrc + (size_t)r*262144);

  f16x8 af[2][4];
  {
    const u16* base = x16f + (size_t)blockIdx.x*16384;
    #pragma unroll
    for (int m=0;m<2;m++)
      #pragma unroll
      for (int kk=0;kk<4;kk++)
        af[m][kk] = *(const f16x8*)(base + (size_t)FRAG(w*2+m, kk, hi, col)*8);
  }

  {
    const unsigned* pr = (const unsigned*)rv;
    #pragma unroll
    for (int jj=0;jj<8;jj++){
      int j = (jj + jblk) & 7;
      unsigned sel = (j&1) ? 0x07060302u : 0x05040100u;
      int dw = j >> 1;
      uint4 ov;
      ov.x = __builtin_amdgcn_perm(pr[4+dw],  pr[0+dw],  sel);
      ov.y = __builtin_amdgcn_perm(pr[12+dw], pr[8+dw],  sel);
      ov.z = __builtin_amdgcn_perm(pr[20+dw], pr[16+dw], sel);
      ov.w = __builtin_amdgcn_perm(pr[28+dw], pr[24+dw], sel);
      int row = jblk*8 + j;
      *(uint4*)(&t_s[row*128 + SWZ8(row, dblk*8)]) = ov;
    }
  }
  __syncthreads();

  {
    int j = tid >> 1, dh = (tid & 1) * 64;
    float s = 0.f, q = 0.f;
    #pragma unroll
    for (int sc=0;sc<8;sc++){
      uint4 v = *(const uint4*)(&t_s[j*128 + SWZ8(j, dh + sc*8)]);
      const u16* ev = (const u16*)&v;
      #pragma unroll
      for (int u=0;u<8;u++){ float f = h2f(ev[u]); s += f; q = fmaf(f,f,q); }
    }
    s += __shfl_xor(s, 1); q += __shfl_xor(q, 1);
    float mu = s * 0.0078125f;
    float rs = rsqrtf(fmaxf(q*0.0078125f - mu*mu, 0.f) + 1e-5f);
    #pragma unroll
    for (int sc=0;sc<8;sc++){
      int db = dh + sc*8;
      u16* p = &t_s[j*128 + SWZ8(j, db)];
      uint4 v = *(uint4*)p;
      u16* ev = (u16*)&v;
      float4 w0 = *(const float4*)(nw + db);
      float4 w1 = *(const float4*)(nw + db + 4);
      float4 b0 = *(const float4*)(nb + db);
      float4 b1 = *(const float4*)(nb + db + 4);
      float wv[8] = {w0.x,w0.y,w0.z,w0.w,w1.x,w1.y,w1.z,w1.w};
      float bv[8] = {b0.x,b0.y,b0.z,b0.w,b1.x,b1.y,b1.z,b1.w};
      #pragma unroll
      for (int u=0;u<8;u++){
        float f = (h2f(ev[u]) - mu)*rs*wv[u] + bv[u];
        ev[u] = f2h(f);
      }
      *(uint4*)p = v;
    }
  }
  __syncthreads();

  #pragma unroll
  for (int ph = 0; ph < 2; ++ph){
    unsigned gt[2][4][2];
    {
      f32x4 gacc[2][4];
      #pragma unroll
      for (int m=0;m<2;m++)
        #pragma unroll
        for (int n=0;n<4;n++) gacc[m][n] = zero4();
      #pragma unroll
      for (int kk=0;kk<4;kk++){
        #pragma unroll
        for (int n=0;n<4;n++){
          f16x8 bv = *(const f16x8*)(WgoF + (size_t)FRAG(ph*4+n,kk,hi,col)*8);
          #pragma unroll
          for (int m=0;m<2;m++)
            gacc[m][n] = __builtin_amdgcn_mfma_f32_16x16x32_f16(af[m][kk], bv, gacc[m][n], 0, 0, 0);
        }
      }
      #pragma unroll
      for (int m=0;m<2;m++)
        #pragma unroll
        for (int n=0;n<4;n++){
          gt[m][n][0] = pk2h(sigm(gacc[m][n][0]), sigm(gacc[m][n][1]));
          gt[m][n][1] = pk2h(sigm(gacc[m][n][2]), sigm(gacc[m][n][3]));
        }
    }
    {
      f32x4 acc[2][4];
      #pragma unroll
      for (int m=0;m<2;m++)
        #pragma unroll
        for (int n=0;n<4;n++) acc[m][n] = zero4();
      #pragma unroll
      for (int kk=0;kk<4;kk++){
        f16x8 a2[2];
        #pragma unroll
        for (int m=0;m<2;m++){
          int row = w*32 + m*16 + col;
          a2[m] = *(const f16x8*)(&t_s[row*128 + SWZ8(row, kk*32 + hi*8)]);
        }
        #pragma unroll
        for (int n=0;n<4;n++){
          f16x8 bv = *(const f16x8*)(WpoF + (size_t)FRAG(ph*4+n,kk,hi,col)*8);
          #pragma unroll
          for (int m=0;m<2;m++)
            acc[m][n] = __builtin_amdgcn_mfma_f32_16x16x32_f16(a2[m], bv, acc[m][n], 0, 0, 0);
        }
      }
      #pragma unroll
      for (int m=0;m<2;m++)
        #pragma unroll
        for (int n=0;n<4;n++)
          #pragma unroll
          for (int j=0;j<4;j++){
            int row = w*32 + m*16 + hi*4 + j, cl = n*16 + col;
            float g = h2f((u16)(gt[m][n][j>>1] >> ((j&1)*16)));
            prod[ph][row*PST + cl] = f2h(acc[m][n][j] * g);
          }
    }
  }
  __syncthreads();

  {
    #pragma unroll
    for (int s=0;s<16;s++){
      int idx = s*256 + tid;
      int row = idx >> 5, c4 = (idx & 31) << 2;
      int ph = c4 >> 6, cc = c4 & 63;
      const u16* p = &prod[ph][row*PST + cc];
      uint2 cv = *(const uint2*)p;
      const u16* ce = (const u16*)&cv;
      float4 o;
      o.x = h2f(ce[0]); o.y = h2f(ce[1]); o.z = h2f(ce[2]); o.w = h2f(ce[3]);
      st_ntf4(out + (rbase + row)*128 + c4, o);
    }
  }
}

extern "C" void kernel_launch(void* const* d_in, const int* in_sizes, int n_in,
                              void* d_out, int out_size, void* d_ws, size_t ws_size,
                              hipStream_t stream){
  const float* x    = (const float*)d_in[0];
  const float* mask = (const float*)d_in[1];
  const float* niw  = (const float*)d_in[2];
  const float* nib  = (const float*)d_in[3];
  const float* piw  = (const float*)d_in[4];
  const float* giw  = (const float*)d_in[5];
  const float* now  = (const float*)d_in[6];
  const float* nob  = (const float*)d_in[7];
  const float* pow_ = (const float*)d_in[8];
  const float* gow  = (const float*)d_in[9];
  float* out = (float*)d_out;

  char* ws = (char*)d_ws;
  u16* a_t  = (u16*)(ws);                          // 64 MB  [128][262144]
  u16* b_t  = (u16*)(ws + (size_t)67108864);       // 64 MB
  u16* t_dm = (u16*)(ws + (size_t)134217728);      // 64 MB  [128][512][512]
  u16* x16f = (u16*)(ws + (size_t)201326592);      // 64 MB  frag-order x_in
  u16* W1F  = (u16*)(ws + (size_t)268435456);      // 128 KB frag-order
  u16* WgoF = W1F + 65536;                         // 32 KB
  u16* WpoF = WgoF + 16384;                        // 32 KB

  k_prep<<<384, 256, 0, stream>>>(piw, giw, gow, pow_, W1F, WgoF, WpoF);
  k_s1<<<2048, 256, 0, stream>>>(x, mask, niw, nib, W1F, a_t, b_t, x16f);
  k_s2<<<dim3(16,128), 256, 0, stream>>>(a_t, b_t, t_dm);
  k_s3<<<2048, 256, 0, stream>>>(t_dm, x16f, WgoF, WpoF, now, nob, out);
}

// Round 24
// 256.915 us; speedup vs baseline: 1.1218x; 1.0433x over previous
//
#include <hip/hip_runtime.h>

typedef unsigned short u16;
typedef _Float16 f16x8 __attribute__((ext_vector_type(8)));
typedef float f32x4 __attribute__((ext_vector_type(4)));
typedef unsigned u32x4 __attribute__((ext_vector_type(4)));

__device__ __forceinline__ u16 f2h(float f){
  _Float16 h = (_Float16)f; u16 u; __builtin_memcpy(&u, &h, 2); return u;
}
__device__ __forceinline__ float h2f(u16 u){
  _Float16 h; __builtin_memcpy(&h, &u, 2); return (float)h;
}
__device__ __forceinline__ unsigned pk2h(float a, float b){
  auto r = __builtin_amdgcn_cvt_pkrtz(a, b);
  unsigned u; __builtin_memcpy(&u, &r, 4); return u;
}
// raw v_rcp_f32 (1 VALU op); 1e-5 rel-err far below f16 output rounding.
__device__ __forceinline__ float sigm(float x){
  return __builtin_amdgcn_rcpf(1.0f + __expf(-x));
}
__device__ __forceinline__ f32x4 zero4(){ f32x4 z; z[0]=0.f; z[1]=0.f; z[2]=0.f; z[3]=0.f; return z; }
// streaming (nontemporal) stores — only where bursts are long/contiguous
// (R23: NT on s1's a_t/b_t staged 16B-granule stores amplified WRITE 196->255MB).
__device__ __forceinline__ void st_nt4(u16* p, uint4 v){
  u32x4 t; __builtin_memcpy(&t, &v, 16);
  __builtin_nontemporal_store(t, (u32x4*)p);
}
__device__ __forceinline__ void st_ntf4(float* p, float4 v){
  f32x4 t; __builtin_memcpy(&t, &v, 16);
  __builtin_nontemporal_store(t, (f32x4*)p);
}

#define SWZ8(row,k) ((k) ^ (((row)&7)<<3))
// fragment index inside a 16-row x 32-k B/A tile set: frag=((n*4+kk)*4+hi)*16+col
#define FRAG(n,kk,hi,col) ((((n)*4+(kk))*4+(hi))*16+(col))

// ---------------- prep: weights straight to MFMA-fragment order ----------------
__global__ void k_prep(const float* __restrict__ p_in, const float* __restrict__ g_in,
                       const float* __restrict__ g_out, const float* __restrict__ p_out,
                       u16* __restrict__ W1F, u16* __restrict__ WgoF, u16* __restrict__ WpoF){
  int t = blockIdx.x*256 + threadIdx.x;
  if (t < 65536){
    int c = t >> 13, u = t & 8191, f = u >> 3, e = u & 7;
    int col = f & 15, hi = (f>>4)&3, kk = (f>>6)&3, n = f>>8;
    int d = c*32 + (n>>1)*16 + col, k = kk*32 + hi*8 + e;
    W1F[t] = f2h((n&1) ? g_in[d*128+k] : p_in[d*128+k]);
  } else if (t < 81920){
    int u = t - 65536, f = u>>3, e = u&7;
    int col = f&15, hi=(f>>4)&3, kk=(f>>6)&3, n=f>>8;
    WgoF[u] = f2h(g_out[(n*16+col)*128 + kk*32+hi*8+e]);
  } else if (t < 98304){
    int u = t - 81920, f = u>>3, e = u&7;
    int col=f&15, hi=(f>>4)&3, kk=(f>>6)&3, n=f>>8;
    WpoF[u] = f2h(p_out[(n*16+col)*128 + kk*32+hi*8+e]);
  }
}

// ---------------- S1: LN + paired in-projection (R18-best stores; NT only x16f) ----------------
__global__ __launch_bounds__(256,2) void k_s1(
    const float* __restrict__ x, const float* __restrict__ mask,
    const float* __restrict__ nw, const float* __restrict__ nb,
    const u16* __restrict__ W1F,
    u16* __restrict__ a_t, u16* __restrict__ b_t, u16* __restrict__ x16f)
{
  __shared__ u16 xh_s[128*128];   // 32KB: x_in f16; first 8KB reused as dbuf staging
  __shared__ float mask_s[128];

  const int tid = threadIdx.x, lane = tid & 63, w = tid >> 6;
  const int col = lane & 15, hi = lane >> 4;
  const int r0 = blockIdx.x * 128;

  if (tid < 128) mask_s[tid] = mask[r0 + tid];

  // LayerNorm — 4 rows/wave in parallel (16 lanes/row, 8 f32/lane, coalesced)
  {
    const int g = lane >> 4, cl = lane & 15;
    float4 nwa = *(const float4*)(nw + cl*8);
    float4 nwb = *(const float4*)(nw + cl*8 + 4);
    float4 nba = *(const float4*)(nb + cl*8);
    float4 nbb = *(const float4*)(nb + cl*8 + 4);
    #pragma unroll
    for (int it = 0; it < 8; ++it){
      int row = w*32 + it*4 + g;
      const float* xr = x + (size_t)(r0+row)*128 + cl*8;
      float4 xa = *(const float4*)xr;
      float4 xb = *(const float4*)(xr + 4);
      float s = ((xa.x+xa.y)+(xa.z+xa.w)) + ((xb.x+xb.y)+(xb.z+xb.w));
      float q = xa.x*xa.x; q = fmaf(xa.y,xa.y,q); q = fmaf(xa.z,xa.z,q); q = fmaf(xa.w,xa.w,q);
      q = fmaf(xb.x,xb.x,q); q = fmaf(xb.y,xb.y,q); q = fmaf(xb.z,xb.z,q); q = fmaf(xb.w,xb.w,q);
      #pragma unroll
      for (int off = 1; off < 16; off <<= 1){ s += __shfl_xor(s, off); q += __shfl_xor(q, off); }
      float mu = s * 0.0078125f;
      float rs = rsqrtf(fmaxf(q*0.0078125f - mu*mu, 0.f) + 1e-5f);
      uint4 pv;
      pv.x = pk2h((xa.x-mu)*rs*nwa.x+nba.x, (xa.y-mu)*rs*nwa.y+nba.y);
      pv.y = pk2h((xa.z-mu)*rs*nwa.z+nba.z, (xa.w-mu)*rs*nwa.w+nba.w);
      pv.z = pk2h((xb.x-mu)*rs*nwb.x+nbb.x, (xb.y-mu)*rs*nwb.y+nbb.y);
      pv.w = pk2h((xb.z-mu)*rs*nwb.z+nbb.z, (xb.w-mu)*rs*nwb.w+nbb.w);
      *(uint4*)(&xh_s[row*128 + SWZ8(row, cl*8)]) = pv;
    }
  }
  __syncthreads();

  // A-fragments register-cached once
  f16x8 af[2][4];
  #pragma unroll
  for (int m = 0; m < 2; ++m){
    #pragma unroll
    for (int kk = 0; kk < 4; ++kk){
      int row = w*32 + m*16 + col;
      af[m][kk] = *(const f16x8*)(&xh_s[row*128 + SWZ8(row, kk*32 + hi*8)]);
    }
  }
  float mk[2][4];
  #pragma unroll
  for (int m = 0; m < 2; ++m)
    #pragma unroll
    for (int j = 0; j < 4; ++j) mk[m][j] = mask_s[w*32 + m*16 + hi*4 + j];

  // x_in -> x16f in fragment order (1KB/wave-instr coalesced, NT ok: full bursts)
  {
    u16* dst = x16f + (size_t)blockIdx.x*16384;
    #pragma unroll
    for (int m = 0; m < 2; ++m)
      #pragma unroll
      for (int kk = 0; kk < 4; ++kk){
        uint4 v; __builtin_memcpy(&v, &af[m][kk], 16);
        st_nt4(dst + (size_t)FRAG(w*2+m, kk, hi, col)*8, v);
      }
  }
  __syncthreads();   // af cached -> xh_s reusable as staging

  for (int c = 0; c < 8; ++c){
    f32x4 acc[2][4];
    #pragma unroll
    for (int m = 0; m < 2; ++m)
      #pragma unroll
      for (int n = 0; n < 4; ++n) acc[m][n] = zero4();

    #pragma unroll
    for (int kk = 0; kk < 4; ++kk){
      f16x8 bf[4];
      #pragma unroll
      for (int n = 0; n < 4; ++n)
        bf[n] = *(const f16x8*)(W1F + c*8192 + (size_t)FRAG(n,kk,hi,col)*8);
      #pragma unroll
      for (int m = 0; m < 2; ++m)
        #pragma unroll
        for (int n = 0; n < 4; ++n)
          acc[m][n] = __builtin_amdgcn_mfma_f32_16x16x32_f16(af[m][kk], bf[n], acc[m][n], 0, 0, 0);
    }

    u16* hbuf = xh_s + (c & 1)*4096;
    #pragma unroll
    for (int m = 0; m < 2; ++m){
      #pragma unroll
      for (int t2 = 0; t2 < 2; ++t2){
        f32x4 pv = acc[m][2*t2], gv = acc[m][2*t2+1];
        int dl = t2*16 + col;
        int rb = w*32 + m*16 + hi*4;
        int ad = dl*128 + (rb ^ ((dl & 15) << 3));
        float h0 = pv[0]*sigm(gv[0])*mk[m][0];
        float h1 = pv[1]*sigm(gv[1])*mk[m][1];
        float h2 = pv[2]*sigm(gv[2])*mk[m][2];
        float h3 = pv[3]*sigm(gv[3])*mk[m][3];
        uint2 uv; uv.x = pk2h(h0, h1); uv.y = pk2h(h2, h3);
        *(uint2*)(&hbuf[ad]) = uv;
      }
    }
    __syncthreads();
    {
      int dl = tid >> 3, seg = (tid & 7)*16;
      int dg = c*32 + dl;
      u16* dst = (dg < 128 ? a_t + (size_t)dg*262144 : b_t + (size_t)(dg-128)*262144) + r0;
      int sw = (dl & 15) << 3;
      uint4 v0 = *(const uint4*)(&hbuf[dl*128 + (seg ^ sw)]);
      uint4 v1 = *(const uint4*)(&hbuf[dl*128 + ((seg + 8) ^ sw)]);
      *(uint4*)(dst + seg)     = v0;   // regular stores: L2 write-combining
      *(uint4*)(dst + seg + 8) = v1;
    }
  }
}

// ---------------- S2: 128 batched NT-GEMMs, dbuf pipeline (NT t_dm store) ----------------
__global__ __launch_bounds__(256,4) void k_s2(
    const u16* __restrict__ a_t, const u16* __restrict__ b_t, u16* __restrict__ t_dm)
{
  __shared__ u16 AB_s[2][2][4096];

  const int tid = threadIdx.x, lane = tid & 63, w = tid >> 6;
  const int col = lane & 15, hi = lane >> 4;

  int bid = blockIdx.x + (blockIdx.y << 4);
  int sw = (bid & 7)*256 + (bid >> 3);
  const int d = sw >> 4;
  const int tile = sw & 15;
  const int ti = (tile >> 2) * 128, tj = (tile & 3) * 128;
  const u16* Ab = a_t + (size_t)d * 262144;
  const u16* Bb = b_t + (size_t)d * 262144;
  const int wr = (w >> 1) * 64, wc = (w & 1) * 64;

  f32x4 acc[4][4];
  #pragma unroll
  for (int m=0;m<4;m++){
    #pragma unroll
    for (int n=0;n<4;n++) acc[m][n] = zero4();
  }

  const int srow = lane >> 2;
  const int scol = (lane & 3) * 8;

  auto STAGE = [&](int buf, int k0){
    #pragma unroll
    for (int j = 0; j < 2; ++j){
      int chunk = w*2 + j;
      int row = chunk*16 + srow;
      int e = scol ^ ((((row >> 1) & 3)) << 3);
      const unsigned int* gpA = (const unsigned int*)(Ab + (size_t)(ti + row)*512 + k0 + e);
      unsigned int* lpA = (unsigned int*)(&AB_s[buf][0][chunk*512]);
      __builtin_amdgcn_global_load_lds((const __attribute__((address_space(1))) unsigned int*)gpA,
                                       (__attribute__((address_space(3))) unsigned int*)lpA, 16, 0, 0);
      const unsigned int* gpB = (const unsigned int*)(Bb + (size_t)(tj + row)*512 + k0 + e);
      unsigned int* lpB = (unsigned int*)(&AB_s[buf][1][chunk*512]);
      __builtin_amdgcn_global_load_lds((const __attribute__((address_space(1))) unsigned int*)gpB,
                                       (__attribute__((address_space(3))) unsigned int*)lpB, 16, 0, 0);
    }
  };

  STAGE(0, 0);
  int cur = 0;
  for (int k0 = 0; k0 < 512; k0 += 32){
    __syncthreads();
    if (k0 + 32 < 512) STAGE(cur ^ 1, k0 + 32);
    f16x8 af[4], bfv[4];
    #pragma unroll
    for (int m=0;m<4;m++){
      int row = wr + m*16 + col;
      af[m] = *(const f16x8*)(&AB_s[cur][0][row*32 + (hi*8 ^ ((((row>>1)&3))<<3))]);
    }
    #pragma unroll
    for (int n=0;n<4;n++){
      int row = wc + n*16 + col;
      bfv[n] = *(const f16x8*)(&AB_s[cur][1][row*32 + (hi*8 ^ ((((row>>1)&3))<<3))]);
    }
    #pragma unroll
    for (int m=0;m<4;m++){
      #pragma unroll
      for (int n=0;n<4;n++)
        acc[m][n] = __builtin_amdgcn_mfma_f32_16x16x32_f16(af[m], bfv[n], acc[m][n], 0, 0, 0);
    }
    cur ^= 1;
  }

  u16* C_s = &AB_s[0][0][0];
  __syncthreads();
  u16* dst0 = t_dm + (size_t)d*262144 + (size_t)ti*512 + tj;
  #pragma unroll
  for (int h = 0; h < 2; ++h){
    if ((w >> 1) == h){
      #pragma unroll
      for (int m=0;m<4;m++){
        #pragma unroll
        for (int n=0;n<4;n++){
          #pragma unroll
          for (int j=0;j<4;j++){
            int row = m*16 + hi*4 + j, cl = wc + n*16 + col;
            C_s[row*136 + cl] = f2h(acc[m][n][j]);
          }
        }
      }
    }
    __syncthreads();
    #pragma unroll
    for (int s=0;s<4;s++){
      int gi = s*256 + tid;
      int row = gi >> 4, seg = (gi & 15) * 8;
      st_nt4(dst0 + (size_t)(h*64 + row)*512 + seg, *(const uint4*)(&C_s[row*136 + seg]));
    }
    if (h == 0) __syncthreads();
  }
}

// ---------------- S3: two n-half passes (R20-best + NT out store) ----------------
#define PST 68
__global__ __launch_bounds__(256,2) void k_s3(
    const u16* __restrict__ t_dm, const u16* __restrict__ x16f,
    const u16* __restrict__ WgoF, const u16* __restrict__ WpoF,
    const float* __restrict__ nw, const float* __restrict__ nb,
    float* __restrict__ out)
{
  __shared__ u16 t_s[128*128];      // 32KB LN'd t tile (SWZ8)
  __shared__ u16 prod[2][128*PST];  // 2 x 17KB gated product halves

  const int tid = threadIdx.x, lane = tid & 63, w = tid >> 6;
  const int col = lane & 15, hi = lane >> 4;
  const size_t rbase = (size_t)blockIdx.x * 128;

  const int dblk = tid >> 4, jblk = tid & 15;
  const u16* tsrc = t_dm + (size_t)(dblk*8)*262144 + rbase + jblk*8;
  uint4 rv[8];
  #pragma unroll
  for (int r=0;r<8;r++) rv[r] = *(const uint4*)(tsrc + (size_t)r*262144);

  f16x8 af[2][4];
  {
    const u16* base = x16f + (size_t)blockIdx.x*16384;
    #pragma unroll
    for (int m=0;m<2;m++)
      #pragma unroll
      for (int kk=0;kk<4;kk++)
        af[m][kk] = *(const f16x8*)(base + (size_t)FRAG(w*2+m, kk, hi, col)*8);
  }

  {
    const unsigned* pr = (const unsigned*)rv;
    #pragma unroll
    for (int jj=0;jj<8;jj++){
      int j = (jj + jblk) & 7;
      unsigned sel = (j&1) ? 0x07060302u : 0x05040100u;
      int dw = j >> 1;
      uint4 ov;
      ov.x = __builtin_amdgcn_perm(pr[4+dw],  pr[0+dw],  sel);
      ov.y = __builtin_amdgcn_perm(pr[12+dw], pr[8+dw],  sel);
      ov.z = __builtin_amdgcn_perm(pr[20+dw], pr[16+dw], sel);
      ov.w = __builtin_amdgcn_perm(pr[28+dw], pr[24+dw], sel);
      int row = jblk*8 + j;
      *(uint4*)(&t_s[row*128 + SWZ8(row, dblk*8)]) = ov;
    }
  }
  __syncthreads();

  {
    int j = tid >> 1, dh = (tid & 1) * 64;
    float s = 0.f, q = 0.f;
    #pragma unroll
    for (int sc=0;sc<8;sc++){
      uint4 v = *(const uint4*)(&t_s[j*128 + SWZ8(j, dh + sc*8)]);
      const u16* ev = (const u16*)&v;
      #pragma unroll
      for (int u=0;u<8;u++){ float f = h2f(ev[u]); s += f; q = fmaf(f,f,q); }
    }
    s += __shfl_xor(s, 1); q += __shfl_xor(q, 1);
    float mu = s * 0.0078125f;
    float rs = rsqrtf(fmaxf(q*0.0078125f - mu*mu, 0.f) + 1e-5f);
    #pragma unroll
    for (int sc=0;sc<8;sc++){
      int db = dh + sc*8;
      u16* p = &t_s[j*128 + SWZ8(j, db)];
      uint4 v = *(uint4*)p;
      u16* ev = (u16*)&v;
      float4 w0 = *(const float4*)(nw + db);
      float4 w1 = *(const float4*)(nw + db + 4);
      float4 b0 = *(const float4*)(nb + db);
      float4 b1 = *(const float4*)(nb + db + 4);
      float wv[8] = {w0.x,w0.y,w0.z,w0.w,w1.x,w1.y,w1.z,w1.w};
      float bv[8] = {b0.x,b0.y,b0.z,b0.w,b1.x,b1.y,b1.z,b1.w};
      #pragma unroll
      for (int u=0;u<8;u++){
        float f = (h2f(ev[u]) - mu)*rs*wv[u] + bv[u];
        ev[u] = f2h(f);
      }
      *(uint4*)p = v;
    }
  }
  __syncthreads();

  #pragma unroll
  for (int ph = 0; ph < 2; ++ph){
    unsigned gt[2][4][2];
    {
      f32x4 gacc[2][4];
      #pragma unroll
      for (int m=0;m<2;m++)
        #pragma unroll
        for (int n=0;n<4;n++) gacc[m][n] = zero4();
      #pragma unroll
      for (int kk=0;kk<4;kk++){
        #pragma unroll
        for (int n=0;n<4;n++){
          f16x8 bv = *(const f16x8*)(WgoF + (size_t)FRAG(ph*4+n,kk,hi,col)*8);
          #pragma unroll
          for (int m=0;m<2;m++)
            gacc[m][n] = __builtin_amdgcn_mfma_f32_16x16x32_f16(af[m][kk], bv, gacc[m][n], 0, 0, 0);
        }
      }
      #pragma unroll
      for (int m=0;m<2;m++)
        #pragma unroll
        for (int n=0;n<4;n++){
          gt[m][n][0] = pk2h(sigm(gacc[m][n][0]), sigm(gacc[m][n][1]));
          gt[m][n][1] = pk2h(sigm(gacc[m][n][2]), sigm(gacc[m][n][3]));
        }
    }
    {
      f32x4 acc[2][4];
      #pragma unroll
      for (int m=0;m<2;m++)
        #pragma unroll
        for (int n=0;n<4;n++) acc[m][n] = zero4();
      #pragma unroll
      for (int kk=0;kk<4;kk++){
        f16x8 a2[2];
        #pragma unroll
        for (int m=0;m<2;m++){
          int row = w*32 + m*16 + col;
          a2[m] = *(const f16x8*)(&t_s[row*128 + SWZ8(row, kk*32 + hi*8)]);
        }
        #pragma unroll
        for (int n=0;n<4;n++){
          f16x8 bv = *(const f16x8*)(WpoF + (size_t)FRAG(ph*4+n,kk,hi,col)*8);
          #pragma unroll
          for (int m=0;m<2;m++)
            acc[m][n] = __builtin_amdgcn_mfma_f32_16x16x32_f16(a2[m], bv, acc[m][n], 0, 0, 0);
        }
      }
      #pragma unroll
      for (int m=0;m<2;m++)
        #pragma unroll
        for (int n=0;n<4;n++)
          #pragma unroll
          for (int j=0;j<4;j++){
            int row = w*32 + m*16 + hi*4 + j, cl = n*16 + col;
            float g = h2f((u16)(gt[m][n][j>>1] >> ((j&1)*16)));
            prod[ph][row*PST + cl] = f2h(acc[m][n][j] * g);
          }
    }
  }
  __syncthreads();

  {
    #pragma unroll
    for (int s=0;s<16;s++){
      int idx = s*256 + tid;
      int row = idx >> 5, c4 = (idx & 31) << 2;
      int ph = c4 >> 6, cc = c4 & 63;
      const u16* p = &prod[ph][row*PST + cc];
      uint2 cv = *(const uint2*)p;
      const u16* ce = (const u16*)&cv;
      float4 o;
      o.x = h2f(ce[0]); o.y = h2f(ce[1]); o.z = h2f(ce[2]); o.w = h2f(ce[3]);
      st_ntf4(out + (rbase + row)*128 + c4, o);
    }
  }
}

extern "C" void kernel_launch(void* const* d_in, const int* in_sizes, int n_in,
                              void* d_out, int out_size, void* d_ws, size_t ws_size,
                              hipStream_t stream){
  const float* x    = (const float*)d_in[0];
  const float* mask = (const float*)d_in[1];
  const float* niw  = (const float*)d_in[2];
  const float* nib  = (const float*)d_in[3];
  const float* piw  = (const float*)d_in[4];
  const float* giw  = (const float*)d_in[5];
  const float* now  = (const float*)d_in[6];
  const float* nob  = (const float*)d_in[7];
  const float* pow_ = (const float*)d_in[8];
  const float* gow  = (const float*)d_in[9];
  float* out = (float*)d_out;

  char* ws = (char*)d_ws;
  u16* a_t  = (u16*)(ws);                          // 64 MB  [128][262144]
  u16* b_t  = (u16*)(ws + (size_t)67108864);       // 64 MB
  u16* t_dm = (u16*)(ws + (size_t)134217728);      // 64 MB  [128][512][512]
  u16* x16f = (u16*)(ws + (size_t)201326592);      // 64 MB  frag-order x_in
  u16* W1F  = (u16*)(ws + (size_t)268435456);      // 128 KB frag-order
  u16* WgoF = W1F + 65536;                         // 32 KB
  u16* WpoF = WgoF + 16384;                        // 32 KB

  k_prep<<<384, 256, 0, stream>>>(piw, giw, gow, pow_, W1F, WgoF, WpoF);
  k_s1<<<2048, 256, 0, stream>>>(x, mask, niw, nib, W1F, a_t, b_t, x16f);
  k_s2<<<dim3(16,128), 256, 0, stream>>>(a_t, b_t, t_dm);
  k_s3<<<2048, 256, 0, stream>>>(t_dm, x16f, WgoF, WpoF, now, nob, out);
}

// Round 25
// 243.337 us; speedup vs baseline: 1.1844x; 1.0558x over previous
//
#include <hip/hip_runtime.h>

typedef unsigned short u16;
typedef _Float16 f16x8 __attribute__((ext_vector_type(8)));
typedef float f32x4 __attribute__((ext_vector_type(4)));
typedef unsigned u32x4 __attribute__((ext_vector_type(4)));

__device__ __forceinline__ u16 f2h(float f){
  _Float16 h = (_Float16)f; u16 u; __builtin_memcpy(&u, &h, 2); return u;
}
__device__ __forceinline__ float h2f(u16 u){
  _Float16 h; __builtin_memcpy(&h, &u, 2); return (float)h;
}
__device__ __forceinline__ unsigned pk2h(float a, float b){
  auto r = __builtin_amdgcn_cvt_pkrtz(a, b);
  unsigned u; __builtin_memcpy(&u, &r, 4); return u;
}
// raw v_rcp_f32 (1 VALU op); 1e-5 rel-err far below f16 output rounding.
__device__ __forceinline__ float sigm(float x){
  return __builtin_amdgcn_rcpf(1.0f + __expf(-x));
}
__device__ __forceinline__ f32x4 zero4(){ f32x4 z; z[0]=0.f; z[1]=0.f; z[2]=0.f; z[3]=0.f; return z; }
// streaming (nontemporal) stores — only where bursts are long/contiguous
__device__ __forceinline__ void st_nt4(u16* p, uint4 v){
  u32x4 t; __builtin_memcpy(&t, &v, 16);
  __builtin_nontemporal_store(t, (u32x4*)p);
}
__device__ __forceinline__ void st_ntf4(float* p, float4 v){
  f32x4 t; __builtin_memcpy(&t, &v, 16);
  __builtin_nontemporal_store(t, (f32x4*)p);
}
// nontemporal loads for read-once streams (keep W1F/WgoF/WpoF L2-resident)
__device__ __forceinline__ float4 ld_ntf4(const float* p){
  f32x4 t = __builtin_nontemporal_load((const f32x4*)p);
  float4 v; __builtin_memcpy(&v, &t, 16); return v;
}
__device__ __forceinline__ uint4 ld_nt4(const u16* p){
  u32x4 t = __builtin_nontemporal_load((const u32x4*)p);
  uint4 v; __builtin_memcpy(&v, &t, 16); return v;
}
__device__ __forceinline__ f16x8 ld_nth8(const u16* p){
  u32x4 t = __builtin_nontemporal_load((const u32x4*)p);
  f16x8 v; __builtin_memcpy(&v, &t, 16); return v;
}

#define SWZ8(row,k) ((k) ^ (((row)&7)<<3))
// fragment index inside a 16-row x 32-k B/A tile set: frag=((n*4+kk)*4+hi)*16+col
#define FRAG(n,kk,hi,col) ((((n)*4+(kk))*4+(hi))*16+(col))

// ---------------- prep: weights straight to MFMA-fragment order ----------------
__global__ void k_prep(const float* __restrict__ p_in, const float* __restrict__ g_in,
                       const float* __restrict__ g_out, const float* __restrict__ p_out,
                       u16* __restrict__ W1F, u16* __restrict__ WgoF, u16* __restrict__ WpoF){
  int t = blockIdx.x*256 + threadIdx.x;
  if (t < 65536){
    int c = t >> 13, u = t & 8191, f = u >> 3, e = u & 7;
    int col = f & 15, hi = (f>>4)&3, kk = (f>>6)&3, n = f>>8;
    int d = c*32 + (n>>1)*16 + col, k = kk*32 + hi*8 + e;
    W1F[t] = f2h((n&1) ? g_in[d*128+k] : p_in[d*128+k]);
  } else if (t < 81920){
    int u = t - 65536, f = u>>3, e = u&7;
    int col = f&15, hi=(f>>4)&3, kk=(f>>6)&3, n=f>>8;
    WgoF[u] = f2h(g_out[(n*16+col)*128 + kk*32+hi*8+e]);
  } else if (t < 98304){
    int u = t - 81920, f = u>>3, e = u&7;
    int col=f&15, hi=(f>>4)&3, kk=(f>>6)&3, n=f>>8;
    WpoF[u] = f2h(p_out[(n*16+col)*128 + kk*32+hi*8+e]);
  }
}

// ---------------- S1: LN + paired in-projection (R24-best; NT x loads) ----------------
__global__ __launch_bounds__(256,2) void k_s1(
    const float* __restrict__ x, const float* __restrict__ mask,
    const float* __restrict__ nw, const float* __restrict__ nb,
    const u16* __restrict__ W1F,
    u16* __restrict__ a_t, u16* __restrict__ b_t, u16* __restrict__ x16f)
{
  __shared__ u16 xh_s[128*128];   // 32KB: x_in f16; first 8KB reused as dbuf staging
  __shared__ float mask_s[128];

  const int tid = threadIdx.x, lane = tid & 63, w = tid >> 6;
  const int col = lane & 15, hi = lane >> 4;
  const int r0 = blockIdx.x * 128;

  if (tid < 128) mask_s[tid] = mask[r0 + tid];

  // LayerNorm — 4 rows/wave in parallel (16 lanes/row, 8 f32/lane, coalesced, NT)
  {
    const int g = lane >> 4, cl = lane & 15;
    float4 nwa = *(const float4*)(nw + cl*8);
    float4 nwb = *(const float4*)(nw + cl*8 + 4);
    float4 nba = *(const float4*)(nb + cl*8);
    float4 nbb = *(const float4*)(nb + cl*8 + 4);
    #pragma unroll
    for (int it = 0; it < 8; ++it){
      int row = w*32 + it*4 + g;
      const float* xr = x + (size_t)(r0+row)*128 + cl*8;
      float4 xa = ld_ntf4(xr);
      float4 xb = ld_ntf4(xr + 4);
      float s = ((xa.x+xa.y)+(xa.z+xa.w)) + ((xb.x+xb.y)+(xb.z+xb.w));
      float q = xa.x*xa.x; q = fmaf(xa.y,xa.y,q); q = fmaf(xa.z,xa.z,q); q = fmaf(xa.w,xa.w,q);
      q = fmaf(xb.x,xb.x,q); q = fmaf(xb.y,xb.y,q); q = fmaf(xb.z,xb.z,q); q = fmaf(xb.w,xb.w,q);
      #pragma unroll
      for (int off = 1; off < 16; off <<= 1){ s += __shfl_xor(s, off); q += __shfl_xor(q, off); }
      float mu = s * 0.0078125f;
      float rs = rsqrtf(fmaxf(q*0.0078125f - mu*mu, 0.f) + 1e-5f);
      uint4 pv;
      pv.x = pk2h((xa.x-mu)*rs*nwa.x+nba.x, (xa.y-mu)*rs*nwa.y+nba.y);
      pv.y = pk2h((xa.z-mu)*rs*nwa.z+nba.z, (xa.w-mu)*rs*nwa.w+nba.w);
      pv.z = pk2h((xb.x-mu)*rs*nwb.x+nbb.x, (xb.y-mu)*rs*nwb.y+nbb.y);
      pv.w = pk2h((xb.z-mu)*rs*nwb.z+nbb.z, (xb.w-mu)*rs*nwb.w+nbb.w);
      *(uint4*)(&xh_s[row*128 + SWZ8(row, cl*8)]) = pv;
    }
  }
  __syncthreads();

  // A-fragments register-cached once
  f16x8 af[2][4];
  #pragma unroll
  for (int m = 0; m < 2; ++m){
    #pragma unroll
    for (int kk = 0; kk < 4; ++kk){
      int row = w*32 + m*16 + col;
      af[m][kk] = *(const f16x8*)(&xh_s[row*128 + SWZ8(row, kk*32 + hi*8)]);
    }
  }
  float mk[2][4];
  #pragma unroll
  for (int m = 0; m < 2; ++m)
    #pragma unroll
    for (int j = 0; j < 4; ++j) mk[m][j] = mask_s[w*32 + m*16 + hi*4 + j];

  // x_in -> x16f in fragment order (1KB/wave-instr coalesced, NT)
  {
    u16* dst = x16f + (size_t)blockIdx.x*16384;
    #pragma unroll
    for (int m = 0; m < 2; ++m)
      #pragma unroll
      for (int kk = 0; kk < 4; ++kk){
        uint4 v; __builtin_memcpy(&v, &af[m][kk], 16);
        st_nt4(dst + (size_t)FRAG(w*2+m, kk, hi, col)*8, v);
      }
  }
  __syncthreads();   // af cached -> xh_s reusable as staging

  for (int c = 0; c < 8; ++c){
    f32x4 acc[2][4];
    #pragma unroll
    for (int m = 0; m < 2; ++m)
      #pragma unroll
      for (int n = 0; n < 4; ++n) acc[m][n] = zero4();

    #pragma unroll
    for (int kk = 0; kk < 4; ++kk){
      f16x8 bf[4];
      #pragma unroll
      for (int n = 0; n < 4; ++n)
        bf[n] = *(const f16x8*)(W1F + c*8192 + (size_t)FRAG(n,kk,hi,col)*8);
      #pragma unroll
      for (int m = 0; m < 2; ++m)
        #pragma unroll
        for (int n = 0; n < 4; ++n)
          acc[m][n] = __builtin_amdgcn_mfma_f32_16x16x32_f16(af[m][kk], bf[n], acc[m][n], 0, 0, 0);
    }

    u16* hbuf = xh_s + (c & 1)*4096;
    #pragma unroll
    for (int m = 0; m < 2; ++m){
      #pragma unroll
      for (int t2 = 0; t2 < 2; ++t2){
        f32x4 pv = acc[m][2*t2], gv = acc[m][2*t2+1];
        int dl = t2*16 + col;
        int rb = w*32 + m*16 + hi*4;
        int ad = dl*128 + (rb ^ ((dl & 15) << 3));
        float h0 = pv[0]*sigm(gv[0])*mk[m][0];
        float h1 = pv[1]*sigm(gv[1])*mk[m][1];
        float h2 = pv[2]*sigm(gv[2])*mk[m][2];
        float h3 = pv[3]*sigm(gv[3])*mk[m][3];
        uint2 uv; uv.x = pk2h(h0, h1); uv.y = pk2h(h2, h3);
        *(uint2*)(&hbuf[ad]) = uv;
      }
    }
    __syncthreads();
    {
      int dl = tid >> 3, seg = (tid & 7)*16;
      int dg = c*32 + dl;
      u16* dst = (dg < 128 ? a_t + (size_t)dg*262144 : b_t + (size_t)(dg-128)*262144) + r0;
      int sw = (dl & 15) << 3;
      uint4 v0 = *(const uint4*)(&hbuf[dl*128 + (seg ^ sw)]);
      uint4 v1 = *(const uint4*)(&hbuf[dl*128 + ((seg + 8) ^ sw)]);
      *(uint4*)(dst + seg)     = v0;   // regular stores: L2 write-combining
      *(uint4*)(dst + seg + 8) = v1;
    }
  }
}

// ---------------- S2: 128 batched NT-GEMMs, dbuf pipeline (NT t_dm store) ----------------
__global__ __launch_bounds__(256,4) void k_s2(
    const u16* __restrict__ a_t, const u16* __restrict__ b_t, u16* __restrict__ t_dm)
{
  __shared__ u16 AB_s[2][2][4096];

  const int tid = threadIdx.x, lane = tid & 63, w = tid >> 6;
  const int col = lane & 15, hi = lane >> 4;

  int bid = blockIdx.x + (blockIdx.y << 4);
  int sw = (bid & 7)*256 + (bid >> 3);
  const int d = sw >> 4;
  const int tile = sw & 15;
  const int ti = (tile >> 2) * 128, tj = (tile & 3) * 128;
  const u16* Ab = a_t + (size_t)d * 262144;
  const u16* Bb = b_t + (size_t)d * 262144;
  const int wr = (w >> 1) * 64, wc = (w & 1) * 64;

  f32x4 acc[4][4];
  #pragma unroll
  for (int m=0;m<4;m++){
    #pragma unroll
    for (int n=0;n<4;n++) acc[m][n] = zero4();
  }

  const int srow = lane >> 2;
  const int scol = (lane & 3) * 8;

  auto STAGE = [&](int buf, int k0){
    #pragma unroll
    for (int j = 0; j < 2; ++j){
      int chunk = w*2 + j;
      int row = chunk*16 + srow;
      int e = scol ^ ((((row >> 1) & 3)) << 3);
      const unsigned int* gpA = (const unsigned int*)(Ab + (size_t)(ti + row)*512 + k0 + e);
      unsigned int* lpA = (unsigned int*)(&AB_s[buf][0][chunk*512]);
      __builtin_amdgcn_global_load_lds((const __attribute__((address_space(1))) unsigned int*)gpA,
                                       (__attribute__((address_space(3))) unsigned int*)lpA, 16, 0, 0);
      const unsigned int* gpB = (const unsigned int*)(Bb + (size_t)(tj + row)*512 + k0 + e);
      unsigned int* lpB = (unsigned int*)(&AB_s[buf][1][chunk*512]);
      __builtin_amdgcn_global_load_lds((const __attribute__((address_space(1))) unsigned int*)gpB,
                                       (__attribute__((address_space(3))) unsigned int*)lpB, 16, 0, 0);
    }
  };

  STAGE(0, 0);
  int cur = 0;
  for (int k0 = 0; k0 < 512; k0 += 32){
    __syncthreads();
    if (k0 + 32 < 512) STAGE(cur ^ 1, k0 + 32);
    f16x8 af[4], bfv[4];
    #pragma unroll
    for (int m=0;m<4;m++){
      int row = wr + m*16 + col;
      af[m] = *(const f16x8*)(&AB_s[cur][0][row*32 + (hi*8 ^ ((((row>>1)&3))<<3))]);
    }
    #pragma unroll
    for (int n=0;n<4;n++){
      int row = wc + n*16 + col;
      bfv[n] = *(const f16x8*)(&AB_s[cur][1][row*32 + (hi*8 ^ ((((row>>1)&3))<<3))]);
    }
    #pragma unroll
    for (int m=0;m<4;m++){
      #pragma unroll
      for (int n=0;n<4;n++)
        acc[m][n] = __builtin_amdgcn_mfma_f32_16x16x32_f16(af[m], bfv[n], acc[m][n], 0, 0, 0);
    }
    cur ^= 1;
  }

  u16* C_s = &AB_s[0][0][0];
  __syncthreads();
  u16* dst0 = t_dm + (size_t)d*262144 + (size_t)ti*512 + tj;
  #pragma unroll
  for (int h = 0; h < 2; ++h){
    if ((w >> 1) == h){
      #pragma unroll
      for (int m=0;m<4;m++){
        #pragma unroll
        for (int n=0;n<4;n++){
          #pragma unroll
          for (int j=0;j<4;j++){
            int row = m*16 + hi*4 + j, cl = wc + n*16 + col;
            C_s[row*136 + cl] = f2h(acc[m][n][j]);
          }
        }
      }
    }
    __syncthreads();
    #pragma unroll
    for (int s=0;s<4;s++){
      int gi = s*256 + tid;
      int row = gi >> 4, seg = (gi & 15) * 8;
      st_nt4(dst0 + (size_t)(h*64 + row)*512 + seg, *(const uint4*)(&C_s[row*136 + seg]));
    }
    if (h == 0) __syncthreads();
  }
}

// ---------------- S3: two n-half passes (R24-best + NT loads) ----------------
#define PST 68
__global__ __launch_bounds__(256,2) void k_s3(
    const u16* __restrict__ t_dm, const u16* __restrict__ x16f,
    const u16* __restrict__ WgoF, const u16* __restrict__ WpoF,
    const float* __restrict__ nw, const float* __restrict__ nb,
    float* __restrict__ out)
{
  __shared__ u16 t_s[128*128];      // 32KB LN'd t tile (SWZ8)
  __shared__ u16 prod[2][128*PST];  // 2 x 17KB gated product halves

  const int tid = threadIdx.x, lane = tid & 63, w = tid >> 6;
  const int col = lane & 15, hi = lane >> 4;
  const size_t rbase = (size_t)blockIdx.x * 128;

  const int dblk = tid >> 4, jblk = tid & 15;
  const u16* tsrc = t_dm + (size_t)(dblk*8)*262144 + rbase + jblk*8;
  uint4 rv[8];
  #pragma unroll
  for (int r=0;r<8;r++) rv[r] = ld_nt4(tsrc + (size_t)r*262144);

  f16x8 af[2][4];
  {
    const u16* base = x16f + (size_t)blockIdx.x*16384;
    #pragma unroll
    for (int m=0;m<2;m++)
      #pragma unroll
      for (int kk=0;kk<4;kk++)
        af[m][kk] = ld_nth8(base + (size_t)FRAG(w*2+m, kk, hi, col)*8);
  }

  {
    const unsigned* pr = (const unsigned*)rv;
    #pragma unroll
    for (int jj=0;jj<8;jj++){
      int j = (jj + jblk) & 7;
      unsigned sel = (j&1) ? 0x07060302u : 0x05040100u;
      int dw = j >> 1;
      uint4 ov;
      ov.x = __builtin_amdgcn_perm(pr[4+dw],  pr[0+dw],  sel);
      ov.y = __builtin_amdgcn_perm(pr[12+dw], pr[8+dw],  sel);
      ov.z = __builtin_amdgcn_perm(pr[20+dw], pr[16+dw], sel);
      ov.w = __builtin_amdgcn_perm(pr[28+dw], pr[24+dw], sel);
      int row = jblk*8 + j;
      *(uint4*)(&t_s[row*128 + SWZ8(row, dblk*8)]) = ov;
    }
  }
  __syncthreads();

  {
    int j = tid >> 1, dh = (tid & 1) * 64;
    float s = 0.f, q = 0.f;
    #pragma unroll
    for (int sc=0;sc<8;sc++){
      uint4 v = *(const uint4*)(&t_s[j*128 + SWZ8(j, dh + sc*8)]);
      const u16* ev = (const u16*)&v;
      #pragma unroll
      for (int u=0;u<8;u++){ float f = h2f(ev[u]); s += f; q = fmaf(f,f,q); }
    }
    s += __shfl_xor(s, 1); q += __shfl_xor(q, 1);
    float mu = s * 0.0078125f;
    float rs = rsqrtf(fmaxf(q*0.0078125f - mu*mu, 0.f) + 1e-5f);
    #pragma unroll
    for (int sc=0;sc<8;sc++){
      int db = dh + sc*8;
      u16* p = &t_s[j*128 + SWZ8(j, db)];
      uint4 v = *(uint4*)p;
      u16* ev = (u16*)&v;
      float4 w0 = *(const float4*)(nw + db);
      float4 w1 = *(const float4*)(nw + db + 4);
      float4 b0 = *(const float4*)(nb + db);
      float4 b1 = *(const float4*)(nb + db + 4);
      float wv[8] = {w0.x,w0.y,w0.z,w0.w,w1.x,w1.y,w1.z,w1.w};
      float bv[8] = {b0.x,b0.y,b0.z,b0.w,b1.x,b1.y,b1.z,b1.w};
      #pragma unroll
      for (int u=0;u<8;u++){
        float f = (h2f(ev[u]) - mu)*rs*wv[u] + bv[u];
        ev[u] = f2h(f);
      }
      *(uint4*)p = v;
    }
  }
  __syncthreads();

  #pragma unroll
  for (int ph = 0; ph < 2; ++ph){
    unsigned gt[2][4][2];
    {
      f32x4 gacc[2][4];
      #pragma unroll
      for (int m=0;m<2;m++)
        #pragma unroll
        for (int n=0;n<4;n++) gacc[m][n] = zero4();
      #pragma unroll
      for (int kk=0;kk<4;kk++){
        #pragma unroll
        for (int n=0;n<4;n++){
          f16x8 bv = *(const f16x8*)(WgoF + (size_t)FRAG(ph*4+n,kk,hi,col)*8);
          #pragma unroll
          for (int m=0;m<2;m++)
            gacc[m][n] = __builtin_amdgcn_mfma_f32_16x16x32_f16(af[m][kk], bv, gacc[m][n], 0, 0, 0);
        }
      }
      #pragma unroll
      for (int m=0;m<2;m++)
        #pragma unroll
        for (int n=0;n<4;n++){
          gt[m][n][0] = pk2h(sigm(gacc[m][n][0]), sigm(gacc[m][n][1]));
          gt[m][n][1] = pk2h(sigm(gacc[m][n][2]), sigm(gacc[m][n][3]));
        }
    }
    {
      f32x4 acc[2][4];
      #pragma unroll
      for (int m=0;m<2;m++)
        #pragma unroll
        for (int n=0;n<4;n++) acc[m][n] = zero4();
      #pragma unroll
      for (int kk=0;kk<4;kk++){
        f16x8 a2[2];
        #pragma unroll
        for (int m=0;m<2;m++){
          int row = w*32 + m*16 + col;
          a2[m] = *(const f16x8*)(&t_s[row*128 + SWZ8(row, kk*32 + hi*8)]);
        }
        #pragma unroll
        for (int n=0;n<4;n++){
          f16x8 bv = *(const f16x8*)(WpoF + (size_t)FRAG(ph*4+n,kk,hi,col)*8);
          #pragma unroll
          for (int m=0;m<2;m++)
            acc[m][n] = __builtin_amdgcn_mfma_f32_16x16x32_f16(a2[m], bv, acc[m][n], 0, 0, 0);
        }
      }
      #pragma unroll
      for (int m=0;m<2;m++)
        #pragma unroll
        for (int n=0;n<4;n++)
          #pragma unroll
          for (int j=0;j<4;j++){
            int row = w*32 + m*16 + hi*4 + j, cl = n*16 + col;
            float g = h2f((u16)(gt[m][n][j>>1] >> ((j&1)*16)));
            prod[ph][row*PST + cl] = f2h(acc[m][n][j] * g);
          }
    }
  }
  __syncthreads();

  {
    #pragma unroll
    for (int s=0;s<16;s++){
      int idx = s*256 + tid;
      int row = idx >> 5, c4 = (idx & 31) << 2;
      int ph = c4 >> 6, cc = c4 & 63;
      const u16* p = &prod[ph][row*PST + cc];
      uint2 cv = *(const uint2*)p;
      const u16* ce = (const u16*)&cv;
      float4 o;
      o.x = h2f(ce[0]); o.y = h2f(ce[1]); o.z = h2f(ce[2]); o.w = h2f(ce[3]);
      st_ntf4(out + (rbase + row)*128 + c4, o);
    }
  }
}

extern "C" void kernel_launch(void* const* d_in, const int* in_sizes, int n_in,
                              void* d_out, int out_size, void* d_ws, size_t ws_size,
                              hipStream_t stream){
  const float* x    = (const float*)d_in[0];
  const float* mask = (const float*)d_in[1];
  const float* niw  = (const float*)d_in[2];
  const float* nib  = (const float*)d_in[3];
  const float* piw  = (const float*)d_in[4];
  const float* giw  = (const float*)d_in[5];
  const float* now  = (const float*)d_in[6];
  const float* nob  = (const float*)d_in[7];
  const float* pow_ = (const float*)d_in[8];
  const float* gow  = (const float*)d_in[9];
  float* out = (float*)d_out;

  char* ws = (char*)d_ws;
  u16* a_t  = (u16*)(ws);                          // 64 MB  [128][262144]
  u16* b_t  = (u16*)(ws + (size_t)67108864);       // 64 MB
  u16* t_dm = (u16*)(ws + (size_t)134217728);      // 64 MB  [128][512][512]
  u16* x16f = (u16*)(ws + (size_t)201326592);      // 64 MB  frag-order x_in
  u16* W1F  = (u16*)(ws + (size_t)268435456);      // 128 KB frag-order
  u16* WgoF = W1F + 65536;                         // 32 KB
  u16* WpoF = WgoF + 16384;                        // 32 KB

  k_prep<<<384, 256, 0, stream>>>(piw, giw, gow, pow_, W1F, WgoF, WpoF);
  k_s1<<<2048, 256, 0, stream>>>(x, mask, niw, nib, W1F, a_t, b_t, x16f);
  k_s2<<<dim3(16,128), 256, 0, stream>>>(a_t, b_t, t_dm);
  k_s3<<<2048, 256, 0, stream>>>(t_dm, x16f, WgoF, WpoF, now, nob, out);
}